// Round 1
// baseline (287.444 us; speedup 1.0000x reference)
//
#include <hip/hip_runtime.h>

typedef unsigned int u32;
typedef unsigned short u16;

#define Cn 128
#define ICn 64
#define Nn 4096
#define Mn 1024

typedef __attribute__((ext_vector_type(8))) short s8v;   // 8 bf16 (4 VGPRs)
typedef __attribute__((ext_vector_type(4))) float f4v;   // 4 fp32 acc

__device__ __forceinline__ float bf2f(u16 u){ union{u32 i; float f;} v; v.i = ((u32)u) << 16; return v.f; }
__device__ __forceinline__ u16 f2bf(float f){ union{float f; u32 i;} v; v.f = f; u32 r = v.i + 0x7fffu + ((v.i >> 16) & 1u); return (u16)(r >> 16); }
__device__ __forceinline__ u32 pk2(float lo, float hi){ return (u32)f2bf(lo) | ((u32)f2bf(hi) << 16); }

// device-scope per-b barrier: all 32 blocks of batch b rendezvous.
__device__ __forceinline__ void gbar(int* flag, int target, int tid)
{
    __threadfence();                 // release: drain this thread's global stores
    __syncthreads();
    if (tid == 0) {
        __hip_atomic_fetch_add(flag, 1, __ATOMIC_RELEASE, __HIP_MEMORY_SCOPE_AGENT);
        while (__hip_atomic_load(flag, __ATOMIC_ACQUIRE, __HIP_MEMORY_SCOPE_AGENT) < target)
            __builtin_amdgcn_s_sleep(2);
    }
    __syncthreads();
    __threadfence();                 // acquire: invalidate caches before reading peers' data
}

// ---------------------------------------------------------------------------
// K1 (MFMA, k_pre folded in): per (row-pair r, half-width wb, batch b):
//   convert w1/w4/w2 f32->bf16 in-block, compute u3 = w5[:64].W3 redundantly,
//   bf16 stage x^T (XOR-swizzled cols: col ^= ((row>>2)&7)<<3 -> 8-way->2-way
//   write conflicts), MFMA dual conv -> pool(a1) -> xgr -> MFMA g = xgr.W2^T;
//   pool(a4) -> p; t = u3.x + c3 (256-thread parallel dot).
// LDS u16 smem[32768] = 64 KB:
//   xsT  @0      [64 lp][136 c]   (swizzled cols)
//   w1t  @8704   [64 ic][136 c]
//   w4t  @17408  [64 ic][136 c]
//   ph   @26112  f32 [32][68]
//   u3s  @30464  f32 [129]        (u3[128] + c3)  -- free tail region
//   phase B: w2t @8704 [128 co][72 ic]; xgr @17920 [16 pw][72 ic]
// ---------------------------------------------------------------------------
__global__ __launch_bounds__(256) void k_conv(
    const float* __restrict__ x,
    const float* __restrict__ w1, const float* __restrict__ b1,
    const float* __restrict__ w3, const float* __restrict__ b3,
    const float* __restrict__ w4, const float* __restrict__ b4,
    const float* __restrict__ w5, const float* __restrict__ w2,
    float* __restrict__ t_o, float* __restrict__ p_o, float* __restrict__ g_o,
    int* __restrict__ flags)
{
    const int tile = blockIdx.x;   // 0..63
    const int r  = tile >> 1;      // row-pair 0..31
    const int wb = tile & 1;       // half-width 0..1
    const int b  = blockIdx.y;
    const int tid = threadIdx.x;

    if (tile == 0 && b == 0 && tid < 8) flags[tid] = 0;   // arm k_mid barriers

    __shared__ __align__(16) u16 smem[32768];
    u16* xsT = smem;               // [64][136]
    u16* w1t = smem + 8704;        // [64][136]
    u16* w4t = smem + 17408;       // [64][136]
    float* ph = (float*)&smem[26112]; // [32][68] f32
    u16* w2t = smem + 8704;        // phase B [128][72]
    u16* xgr = smem + 17920;       // phase B [16][72]
    float* u3s = (float*)&smem[30464]; // [129] f32

    // ---- stage x^T as bf16, swizzled: col' = c ^ (((row>>2)&7)<<3) ----
    #pragma unroll
    for (int it = 0; it < 8; ++it) {
        int f = tid + 256 * it;        // 2048 float4s
        int c = f >> 4, rem = f & 15;
        int rl = rem >> 3, wq = rem & 7;
        const float* src = x + ((size_t)(b * Cn + c)) * Nn + (2 * r + rl) * 64 + 32 * wb + 4 * wq;
        float4 v = *(const float4*)src;
        int lp0 = rl * 32 + 4 * wq;
        int cS = c ^ (wq << 3);        // ((lp0+k)>>2)&7 == wq for k=0..3
        xsT[(lp0 + 0) * 136 + cS] = f2bf(v.x);
        xsT[(lp0 + 1) * 136 + cS] = f2bf(v.y);
        xsT[(lp0 + 2) * 136 + cS] = f2bf(v.z);
        xsT[(lp0 + 3) * 136 + cS] = f2bf(v.w);
    }
    // ---- stage W1, W4: f32 load + convert + ds_write_b128 ----
    #pragma unroll
    for (int it = 0; it < 4; ++it) {
        int f = tid + 256 * it;        // 1024 groups of 8: ic = f>>4, cq = f&15
        int ic = f >> 4, cq = f & 15;
        const float4* s1 = (const float4*)&w1[f * 8];
        const float4* s4 = (const float4*)&w4[f * 8];
        float4 a0 = s1[0], a1v = s1[1];
        float4 d0 = s4[0], d1v = s4[1];
        uint4 A, D;
        A.x = pk2(a0.x, a0.y); A.y = pk2(a0.z, a0.w); A.z = pk2(a1v.x, a1v.y); A.w = pk2(a1v.z, a1v.w);
        D.x = pk2(d0.x, d0.y); D.y = pk2(d0.z, d0.w); D.z = pk2(d1v.x, d1v.y); D.w = pk2(d1v.z, d1v.w);
        *(uint4*)&w1t[ic * 136 + 8 * cq] = A;
        *(uint4*)&w4t[ic * 136 + 8 * cq] = D;
    }
    // ---- u3 = w5[:64].W3 (redundant per block, L2-resident), c3 = w5.b3 ----
    if (tid < 128) {
        float s = 0.f;
        #pragma unroll 16
        for (int ic = 0; ic < 64; ++ic) s += w5[ic] * w3[ic * Cn + tid];
        u3s[tid] = s;
    } else if (tid == 128) {
        float s = 0.f;
        #pragma unroll 16
        for (int ic = 0; ic < 64; ++ic) s += w5[ic] * b3[ic];
        u3s[128] = s;
    }
    __syncthreads();

    const int lane = tid & 63;
    const int wv   = tid >> 6;         // wave 0..3 -> lp block [16wv,16wv+16)
    const int col  = lane & 15;
    const int quad = lane >> 4;

    // ---- dual conv MFMA: D[ic][lp] ----
    f4v acc1[4] = {}, acc4[4] = {};
    const u16* xrow = &xsT[(16 * wv + col) * 136];
    const int xsw = (((16 * wv + col) >> 2) & 7) << 3;
    #pragma unroll
    for (int kb = 0; kb < 4; ++kb) {
        s8v bx = *(const s8v*)&xrow[(kb * 32 + quad * 8) ^ xsw];
        #pragma unroll
        for (int icb = 0; icb < 4; ++icb) {
            s8v a1 = *(const s8v*)&w1t[(icb * 16 + col) * 136 + kb * 32 + quad * 8];
            s8v a4 = *(const s8v*)&w4t[(icb * 16 + col) * 136 + kb * 32 + quad * 8];
            acc1[icb] = __builtin_amdgcn_mfma_f32_16x16x32_bf16(a1, bx, acc1[icb], 0, 0, 0);
            acc4[icb] = __builtin_amdgcn_mfma_f32_16x16x32_bf16(a4, bx, acc4[icb], 0, 0, 0);
        }
    }
    __syncthreads();   // MFMA LDS reads done; w1t/w4t dead

    // ---- a1: horizontal pair max in-register, write half-pool to ph ----
    const int lp = 16 * wv + col;
    const int rl = lp >> 5, wl = lp & 31, pw = wl >> 1;
    const bool wr = (wl & 1) == 0;
    #pragma unroll
    for (int icb = 0; icb < 4; ++icb)
        #pragma unroll
        for (int reg = 0; reg < 4; ++reg) {
            float v = acc1[icb][reg];
            float vm = fmaxf(v, __shfl_xor(v, 1, 64));
            if (wr) ph[(rl * 16 + pw) * 68 + icb * 16 + quad * 4 + reg] = vm;
        }
    __syncthreads();

    // ---- xgr = vertical pool + bias (bf16) ----
    #pragma unroll
    for (int it = 0; it < 4; ++it) {
        int e = tid + 256 * it;        // 1024: pw = e>>6, ic = e&63
        int pwq = e >> 6, ic = e & 63;
        float v = fmaxf(ph[pwq * 68 + ic], ph[(16 + pwq) * 68 + ic]) + b1[ic];
        xgr[pwq * 72 + ic] = f2bf(v);
    }
    // ---- t = u3.x + c3, all 256 threads (4 lanes per pixel) ----
    {
        int px = tid >> 2, part = tid & 3;
        const int tsw = ((px >> 2) & 7) << 3;
        const u16* xr = &xsT[px * 136];
        float s = 0.f;
        #pragma unroll
        for (int cq = 0; cq < 4; ++cq) {
            int u = part * 32 + cq * 8;
            s8v xv = *(const s8v*)&xr[u ^ tsw];
            #pragma unroll
            for (int j = 0; j < 8; ++j) s += u3s[u + j] * bf2f((u16)xv[j]);
        }
        s += __shfl_xor(s, 1, 64);
        s += __shfl_xor(s, 2, 64);
        if (part == 0)
            t_o[(size_t)b * Nn + (2 * r + (px >> 5)) * 64 + 32 * wb + (px & 31)] = s + u3s[128];
    }
    __syncthreads();   // xgr ready; ph consumed

    // ---- stage W2 (f32->bf16) [co][72]; a4 half-pool -> ph ----
    #pragma unroll
    for (int it = 0; it < 4; ++it) {
        int f = tid + 256 * it;        // 1024 groups: co = f>>3, iq = f&7
        int co = f >> 3, iq = f & 7;
        const float4* s2 = (const float4*)&w2[f * 8];
        float4 a0 = s2[0], a1v = s2[1];
        uint4 V;
        V.x = pk2(a0.x, a0.y); V.y = pk2(a0.z, a0.w); V.z = pk2(a1v.x, a1v.y); V.w = pk2(a1v.z, a1v.w);
        *(uint4*)&w2t[co * 72 + 8 * iq] = V;
    }
    #pragma unroll
    for (int icb = 0; icb < 4; ++icb)
        #pragma unroll
        for (int reg = 0; reg < 4; ++reg) {
            float v = acc4[icb][reg];
            float vm = fmaxf(v, __shfl_xor(v, 1, 64));
            if (wr) ph[(rl * 16 + pw) * 68 + icb * 16 + quad * 4 + reg] = vm;
        }
    __syncthreads();

    // ---- g = xgr . W2^T via MFMA: wave wv -> co blocks {2wv, 2wv+1} ----
    #pragma unroll
    for (int cob2 = 0; cob2 < 2; ++cob2) {
        int cob = 2 * wv + cob2;
        f4v gacc = {};
        #pragma unroll
        for (int kb = 0; kb < 2; ++kb) {
            s8v a  = *(const s8v*)&xgr[col * 72 + kb * 32 + quad * 8];
            s8v bb = *(const s8v*)&w2t[(cob * 16 + col) * 72 + kb * 32 + quad * 8];
            gacc = __builtin_amdgcn_mfma_f32_16x16x32_bf16(a, bb, gacc, 0, 0, 0);
        }
        #pragma unroll
        for (int reg = 0; reg < 4; ++reg) {
            int pwr = quad * 4 + reg;
            int m = r * 32 + wb * 16 + pwr;
            g_o[((size_t)b * Mn + m) * 128 + cob * 16 + col] = gacc[reg];
        }
    }

    // ---- p from a4 pool ----
    if (tid < 16) {
        float s = 0.f;
        #pragma unroll 8
        for (int ic = 0; ic < 64; ++ic) {
            float pv = fmaxf(ph[tid * 68 + ic], ph[(16 + tid) * 68 + ic]) + b4[ic];
            s += w5[64 + ic] * pv;
        }
        p_o[(size_t)b * Mn + r * 32 + wb * 16 + tid] = s;
    }
}

// ---------------------------------------------------------------------------
// K2 (fused rank + chunk-sums + suffix-walk + final), grid (32 seg, 8 b).
// Per-b device barriers: flag[b] rises 32 -> 64 -> 96.
// LDS byte layout (39168 B):
//   pls/psl @0      f32[1024]                 (phase 0 / phase F)
//   gs      @4096   f32[32*128]               (A, C)    | sa_s @4096 [32][129] (F)
//   pl      @20480  f32[32]; pml @20608 int[32]; red @20736 f32[512]   (A, C)
//   sb_s    @20608+16512 -> @20608?  -- see offsets below (F only, peers dead)
//   tl @37120, kl @37632, sc @38144, bs @38656                         (F)
// ---------------------------------------------------------------------------
__global__ __launch_bounds__(256) void k_mid(
    const float* __restrict__ x, const float* __restrict__ t,
    const float* __restrict__ p, const float* __restrict__ g,
    float* __restrict__ ps, int* __restrict__ perm,
    float* __restrict__ csa, float* __restrict__ csb,
    float* __restrict__ SA, float* __restrict__ SB,
    const float* __restrict__ b2, const float* __restrict__ gamma, const float* __restrict__ beta,
    const float* __restrict__ mean, const float* __restrict__ var,
    int* __restrict__ flags, float* __restrict__ out)
{
    const int seg = blockIdx.x;    // 0..31 (= final-phase n-tile)
    const int b   = blockIdx.y;    // 0..7
    const int tid = threadIdx.x;
    int* flag = flags + b;

    __shared__ __align__(16) char smem[39168];
    float* pls  = (float*)smem;                     // [1024]
    float* gs   = (float*)(smem + 4096);            // [32*128]
    float* pl   = (float*)(smem + 20480);           // [32]
    int*   pml  = (int*)  (smem + 20608);           // [32]
    float* red  = (float*)(smem + 20736);           // [512] (A/B halves)
    float* sa_s = (float*)(smem + 4096);            // F: [32][129]
    float* sb_s = (float*)(smem + 4096 + 16512);    // F: [32][129]
    float* tl   = (float*)(smem + 37120);           // F: [128]
    int*   kl   = (int*)  (smem + 37632);           // F: [128]
    float* sc   = (float*)(smem + 38144);           // F: [128]
    float* bs   = (float*)(smem + 38656);           // F: [128]

    // ===== phase 0: rank the block's 32 m's (8 lanes per m) =====
    #pragma unroll
    for (int it = 0; it < 4; ++it) pls[tid + 256 * it] = p[b * 1024 + tid + 256 * it];
    __syncthreads();
    {
        const int m = seg * 32 + (tid >> 3);
        const int sub = tid & 7;
        const float key = pls[m];
        int rank = 0;
        #pragma unroll 8
        for (int jj = 0; jj < 128; ++jj) {
            int j = sub + jj * 8;          // interleaved: 8 distinct banks across wave
            float v = pls[j];
            rank += (v < key || (v == key && j < m)) ? 1 : 0;
        }
        rank += __shfl_xor(rank, 1, 64);
        rank += __shfl_xor(rank, 2, 64);
        rank += __shfl_xor(rank, 4, 64);
        if (sub == 0) {
            ps[b * 1024 + rank]   = key;
            perm[b * 1024 + rank] = m;
        }
    }
    gbar(flag, 32, tid);

    // ===== phase A: stage sorted seg + gathered g rows, chunk sums =====
    if (tid < 32) {
        pl[tid]  = ps[b * 1024 + seg * 32 + tid];
        pml[tid] = perm[b * 1024 + seg * 32 + tid];
    }
    __syncthreads();
    #pragma unroll
    for (int it = 0; it < 16; ++it) {
        int f = tid + 256 * it;
        int jj = f >> 7, co = f & 127;
        gs[jj * 128 + co] = g[((size_t)b * Mn + pml[jj]) * 128 + co];
    }
    __syncthreads();
    {
        const int co = tid & 127, jh = tid >> 7;
        float sA = 0.f, sB = 0.f;
        #pragma unroll
        for (int jj = jh * 16; jj < jh * 16 + 16; ++jj) {
            float gv = gs[jj * 128 + co];
            sA += gv; sB += pl[jj] * gv;
        }
        red[jh * 128 + co]       = sA;
        red[256 + jh * 128 + co] = sB;
    }
    __syncthreads();
    if (tid < 128) {
        csa[(b * 32 + seg) * 128 + tid] = red[tid] + red[128 + tid];
        csb[(b * 32 + seg) * 128 + tid] = red[256 + tid] + red[384 + tid];
    }
    gbar(flag, 64, tid);

    // ===== phase C: suffix-sum walk (gs still staged) =====
    {
        const int co = tid & 127;
        if (tid < 128) {
            float rA = 0.f;
            for (int s2 = seg + 1; s2 < 32; ++s2) rA += csa[(b * 32 + s2) * 128 + co];
            if (seg == 31) SA[((size_t)b * 1025 + 1024) * 128 + co] = 0.f;
            #pragma unroll
            for (int jj = 31; jj >= 0; --jj) {
                rA += gs[jj * 128 + co];
                SA[((size_t)b * 1025 + seg * 32 + jj) * 128 + co] = rA;
            }
        } else {
            float rB = 0.f;
            for (int s2 = seg + 1; s2 < 32; ++s2) rB += csb[(b * 32 + s2) * 128 + co];
            if (seg == 31) SB[((size_t)b * 1025 + 1024) * 128 + co] = 0.f;
            #pragma unroll
            for (int jj = 31; jj >= 0; --jj) {
                rB += pl[jj] * gs[jj * 128 + co];
                SB[((size_t)b * 1025 + seg * 32 + jj) * 128 + co] = rB;
            }
        }
    }
    gbar(flag, 96, tid);

    // ===== phase F: final output tile (nt = seg) =====
    const int n0 = seg * 128;
    #pragma unroll
    for (int it = 0; it < 4; ++it) pls[tid + 256 * it] = ps[b * 1024 + tid + 256 * it];
    __syncthreads();
    if (tid < 128) {
        float tv = t[(size_t)b * Nn + n0 + tid];
        tl[tid] = tv;
        float key = -tv;
        int lo = 0, hi = 1024;
        while (lo < hi) { int mid = (lo + hi) >> 1; if (pls[mid] > key) hi = mid; else lo = mid + 1; }
        kl[tid] = lo;
    } else {
        int co = tid - 128;
        float s = gamma[co] * rsqrtf(var[co] + 1e-5f);
        sc[co] = s;
        bs[co] = (b2[co] - mean[co]) * s + beta[co];
    }
    __syncthreads();

    const float invM = 1.0f / 1024.0f;
    for (int sub = 0; sub < 4; ++sub) {
        #pragma unroll
        for (int it = 0; it < 16; ++it) {
            int f = tid + 256 * it;
            int rowl = f >> 7, co = f & 127;
            int k = kl[sub * 32 + rowl];
            sa_s[rowl * 129 + co] = SA[((size_t)b * 1025 + k) * 128 + co];
            sb_s[rowl * 129 + co] = SB[((size_t)b * 1025 + k) * 128 + co];
        }
        __syncthreads();
        #pragma unroll
        for (int it = 0; it < 4; ++it) {
            int f = tid + 256 * it;
            int co = f >> 3, nn0 = (f & 7) * 4;
            size_t gidx = ((size_t)b * Cn + co) * Nn + n0 + sub * 32 + nn0;
            float4 xv = *(const float4*)&x[gidx];
            float scv = sc[co], bsv = bs[co];
            float v0 = (tl[sub*32+nn0+0] * sa_s[(nn0+0)*129+co] + sb_s[(nn0+0)*129+co]) * invM;
            float v1 = (tl[sub*32+nn0+1] * sa_s[(nn0+1)*129+co] + sb_s[(nn0+1)*129+co]) * invM;
            float v2 = (tl[sub*32+nn0+2] * sa_s[(nn0+2)*129+co] + sb_s[(nn0+2)*129+co]) * invM;
            float v3 = (tl[sub*32+nn0+3] * sa_s[(nn0+3)*129+co] + sb_s[(nn0+3)*129+co]) * invM;
            float4 o;
            o.x = v0 * scv + bsv + xv.x;
            o.y = v1 * scv + bsv + xv.y;
            o.z = v2 * scv + bsv + xv.z;
            o.w = v3 * scv + bsv + xv.w;
            *(float4*)&out[gidx] = o;
        }
        __syncthreads();
    }
}

// ---------------------------------------------------------------------------
extern "C" void kernel_launch(void* const* d_in, const int* in_sizes, int n_in,
                              void* d_out, int out_size, void* d_ws, size_t ws_size,
                              hipStream_t stream)
{
    const float* x  = (const float*)d_in[0];
    const float* w1 = (const float*)d_in[1];
    const float* b1 = (const float*)d_in[2];
    const float* w3 = (const float*)d_in[3];
    const float* b3 = (const float*)d_in[4];
    const float* w4 = (const float*)d_in[5];
    const float* b4 = (const float*)d_in[6];
    const float* w5 = (const float*)d_in[7];
    const float* w2 = (const float*)d_in[8];
    const float* b2 = (const float*)d_in[9];
    const float* gm = (const float*)d_in[10];
    const float* bt = (const float*)d_in[11];
    const float* mn = (const float*)d_in[12];
    const float* vr = (const float*)d_in[13];
    float* out = (float*)d_out;

    float* ws = (float*)d_ws;
    const size_t FTOT = 3823872;           // floats (~15.3 MB)
    if (ws_size < FTOT * sizeof(float)) return;

    float* t_w  = ws;                      // 32768
    float* p_w  = ws + 32768;              // 8192
    float* ps_w = ws + 40960;              // 8192
    int*   pm_w = (int*)(ws + 49152);      // 8192
    float* g_w  = ws + 581632;             // 1048576
    float* csa  = ws + 1630208;            // 32768
    float* csb  = ws + 1662976;            // 32768
    float* SAp  = ws + 1695744;            // 1049600
    float* SBp  = ws + 2745344;            // 1049600
    int*   flags = (int*)(ws + 3811328);   // 8 ints

    k_conv<<<dim3(64, 8), 256, 0, stream>>>(x, w1, b1, w3, b3, w4, b4, w5, w2,
                                            t_w, p_w, g_w, flags);
    k_mid <<<dim3(32, 8), 256, 0, stream>>>(x, t_w, p_w, g_w, ps_w, pm_w,
                                            csa, csb, SAp, SBp,
                                            b2, gm, bt, mn, vr, flags, out);
}

// Round 2
// 129.396 us; speedup vs baseline: 2.2214x; 2.2214x over previous
//
#include <hip/hip_runtime.h>

typedef unsigned int u32;
typedef unsigned short u16;

#define Cn 128
#define ICn 64
#define Nn 4096
#define Mn 1024

typedef __attribute__((ext_vector_type(8))) short s8v;   // 8 bf16 (4 VGPRs)
typedef __attribute__((ext_vector_type(4))) float f4v;   // 4 fp32 acc

__device__ __forceinline__ float bf2f(u16 u){ union{u32 i; float f;} v; v.i = ((u32)u) << 16; return v.f; }
__device__ __forceinline__ u16 f2bf(float f){ union{float f; u32 i;} v; v.f = f; u32 r = v.i + 0x7fffu + ((v.i >> 16) & 1u); return (u16)(r >> 16); }
__device__ __forceinline__ u32 pk2(float lo, float hi){ return (u32)f2bf(lo) | ((u32)f2bf(hi) << 16); }

// ---------------------------------------------------------------------------
// K1 (MFMA, weight-prep folded in): per (row-pair r, half-width wb, batch b):
//   convert w1/w4/w2 f32->bf16 in-block (L2-resident), compute u3 = w5[:64].W3
//   redundantly, bf16 stage x^T with XOR-swizzled cols (col ^= (((row)>>2)&7)<<3
//   -> write conflicts 16-way -> ~4-way, MFMA-read 8-way -> ~2-way),
//   MFMA dual conv -> pool(a1) -> xgr -> MFMA g = xgr.W2^T; pool(a4) -> p;
//   t = u3.x + c3 (256-thread parallel dot).
// LDS u16 smem[32768] = 64 KB:
//   xsT  @0      [64 lp][136 c]   (swizzled cols)
//   w1t  @8704   [64 ic][136 c]
//   w4t  @17408  [64 ic][136 c]
//   ph   @26112  f32 [32][68]
//   u3s  @30464  f32 [129]        (u3[128] + c3)
//   phase B: w2t @8704 [128 co][72 ic]; xgr @17920 [16 pw][72 ic]
// ---------------------------------------------------------------------------
__global__ __launch_bounds__(256) void k_conv(
    const float* __restrict__ x,
    const float* __restrict__ w1, const float* __restrict__ b1,
    const float* __restrict__ w3, const float* __restrict__ b3,
    const float* __restrict__ w4, const float* __restrict__ b4,
    const float* __restrict__ w5, const float* __restrict__ w2,
    float* __restrict__ t_o, float* __restrict__ p_o, float* __restrict__ g_o)
{
    const int tile = blockIdx.x;   // 0..63
    const int r  = tile >> 1;      // row-pair 0..31
    const int wb = tile & 1;       // half-width 0..1
    const int b  = blockIdx.y;
    const int tid = threadIdx.x;

    __shared__ __align__(16) u16 smem[32768];
    u16* xsT = smem;               // [64][136]
    u16* w1t = smem + 8704;        // [64][136]
    u16* w4t = smem + 17408;       // [64][136]
    float* ph = (float*)&smem[26112]; // [32][68] f32
    u16* w2t = smem + 8704;        // phase B [128][72]
    u16* xgr = smem + 17920;       // phase B [16][72]
    float* u3s = (float*)&smem[30464]; // [129] f32

    // ---- stage x^T as bf16, swizzled: col' = c ^ (((row>>2)&7)<<3) ----
    #pragma unroll
    for (int it = 0; it < 8; ++it) {
        int f = tid + 256 * it;        // 2048 float4s
        int c = f >> 4, rem = f & 15;
        int rl = rem >> 3, wq = rem & 7;
        const float* src = x + ((size_t)(b * Cn + c)) * Nn + (2 * r + rl) * 64 + 32 * wb + 4 * wq;
        float4 v = *(const float4*)src;
        int lp0 = rl * 32 + 4 * wq;
        int cS = c ^ (wq << 3);        // ((lp0+k)>>2)&7 == wq for k=0..3
        xsT[(lp0 + 0) * 136 + cS] = f2bf(v.x);
        xsT[(lp0 + 1) * 136 + cS] = f2bf(v.y);
        xsT[(lp0 + 2) * 136 + cS] = f2bf(v.z);
        xsT[(lp0 + 3) * 136 + cS] = f2bf(v.w);
    }
    // ---- stage W1, W4: f32 load + convert + ds_write_b128 ----
    #pragma unroll
    for (int it = 0; it < 4; ++it) {
        int f = tid + 256 * it;        // 1024 groups of 8: ic = f>>4, cq = f&15
        int ic = f >> 4, cq = f & 15;
        const float4* s1 = (const float4*)&w1[f * 8];
        const float4* s4 = (const float4*)&w4[f * 8];
        float4 a0 = s1[0], a1v = s1[1];
        float4 d0 = s4[0], d1v = s4[1];
        uint4 A, D;
        A.x = pk2(a0.x, a0.y); A.y = pk2(a0.z, a0.w); A.z = pk2(a1v.x, a1v.y); A.w = pk2(a1v.z, a1v.w);
        D.x = pk2(d0.x, d0.y); D.y = pk2(d0.z, d0.w); D.z = pk2(d1v.x, d1v.y); D.w = pk2(d1v.z, d1v.w);
        *(uint4*)&w1t[ic * 136 + 8 * cq] = A;
        *(uint4*)&w4t[ic * 136 + 8 * cq] = D;
    }
    // ---- u3 = w5[:64].W3 (redundant per block, L2-resident), c3 = w5.b3 ----
    if (tid < 128) {
        float s = 0.f;
        #pragma unroll 16
        for (int ic = 0; ic < 64; ++ic) s += w5[ic] * w3[ic * Cn + tid];
        u3s[tid] = s;
    } else if (tid == 128) {
        float s = 0.f;
        #pragma unroll 16
        for (int ic = 0; ic < 64; ++ic) s += w5[ic] * b3[ic];
        u3s[128] = s;
    }
    __syncthreads();

    const int lane = tid & 63;
    const int wv   = tid >> 6;         // wave 0..3 -> lp block [16wv,16wv+16)
    const int col  = lane & 15;
    const int quad = lane >> 4;

    // ---- dual conv MFMA: D[ic][lp] ----
    f4v acc1[4] = {}, acc4[4] = {};
    const u16* xrow = &xsT[(16 * wv + col) * 136];
    const int xsw = (((16 * wv + col) >> 2) & 7) << 3;
    #pragma unroll
    for (int kb = 0; kb < 4; ++kb) {
        s8v bx = *(const s8v*)&xrow[(kb * 32 + quad * 8) ^ xsw];
        #pragma unroll
        for (int icb = 0; icb < 4; ++icb) {
            s8v a1 = *(const s8v*)&w1t[(icb * 16 + col) * 136 + kb * 32 + quad * 8];
            s8v a4 = *(const s8v*)&w4t[(icb * 16 + col) * 136 + kb * 32 + quad * 8];
            acc1[icb] = __builtin_amdgcn_mfma_f32_16x16x32_bf16(a1, bx, acc1[icb], 0, 0, 0);
            acc4[icb] = __builtin_amdgcn_mfma_f32_16x16x32_bf16(a4, bx, acc4[icb], 0, 0, 0);
        }
    }
    __syncthreads();   // MFMA LDS reads done; w1t/w4t dead

    // ---- a1: horizontal pair max in-register, write half-pool to ph ----
    const int lp = 16 * wv + col;
    const int rl = lp >> 5, wl = lp & 31, pw = wl >> 1;
    const bool wr = (wl & 1) == 0;
    #pragma unroll
    for (int icb = 0; icb < 4; ++icb)
        #pragma unroll
        for (int reg = 0; reg < 4; ++reg) {
            float v = acc1[icb][reg];
            float vm = fmaxf(v, __shfl_xor(v, 1, 64));
            if (wr) ph[(rl * 16 + pw) * 68 + icb * 16 + quad * 4 + reg] = vm;
        }
    __syncthreads();

    // ---- xgr = vertical pool + bias (bf16) ----
    #pragma unroll
    for (int it = 0; it < 4; ++it) {
        int e = tid + 256 * it;        // 1024: pw = e>>6, ic = e&63
        int pwq = e >> 6, ic = e & 63;
        float v = fmaxf(ph[pwq * 68 + ic], ph[(16 + pwq) * 68 + ic]) + b1[ic];
        xgr[pwq * 72 + ic] = f2bf(v);
    }
    // ---- t = u3.x + c3, all 256 threads (4 lanes per pixel) ----
    {
        int px = tid >> 2, part = tid & 3;
        const int tsw = ((px >> 2) & 7) << 3;
        const u16* xr = &xsT[px * 136];
        float s = 0.f;
        #pragma unroll
        for (int cq = 0; cq < 4; ++cq) {
            int u = part * 32 + cq * 8;
            s8v xv = *(const s8v*)&xr[u ^ tsw];
            #pragma unroll
            for (int j = 0; j < 8; ++j) s += u3s[u + j] * bf2f((u16)xv[j]);
        }
        s += __shfl_xor(s, 1, 64);
        s += __shfl_xor(s, 2, 64);
        if (part == 0)
            t_o[(size_t)b * Nn + (2 * r + (px >> 5)) * 64 + 32 * wb + (px & 31)] = s + u3s[128];
    }
    __syncthreads();   // xgr ready; ph consumed

    // ---- stage W2 (f32->bf16) [co][72]; a4 half-pool -> ph ----
    #pragma unroll
    for (int it = 0; it < 4; ++it) {
        int f = tid + 256 * it;        // 1024 groups: co = f>>3, iq = f&7
        int co = f >> 3, iq = f & 7;
        const float4* s2 = (const float4*)&w2[f * 8];
        float4 a0 = s2[0], a1v = s2[1];
        uint4 V;
        V.x = pk2(a0.x, a0.y); V.y = pk2(a0.z, a0.w); V.z = pk2(a1v.x, a1v.y); V.w = pk2(a1v.z, a1v.w);
        *(uint4*)&w2t[co * 72 + 8 * iq] = V;
    }
    #pragma unroll
    for (int icb = 0; icb < 4; ++icb)
        #pragma unroll
        for (int reg = 0; reg < 4; ++reg) {
            float v = acc4[icb][reg];
            float vm = fmaxf(v, __shfl_xor(v, 1, 64));
            if (wr) ph[(rl * 16 + pw) * 68 + icb * 16 + quad * 4 + reg] = vm;
        }
    __syncthreads();

    // ---- g = xgr . W2^T via MFMA: wave wv -> co blocks {2wv, 2wv+1} ----
    #pragma unroll
    for (int cob2 = 0; cob2 < 2; ++cob2) {
        int cob = 2 * wv + cob2;
        f4v gacc = {};
        #pragma unroll
        for (int kb = 0; kb < 2; ++kb) {
            s8v a  = *(const s8v*)&xgr[col * 72 + kb * 32 + quad * 8];
            s8v bb = *(const s8v*)&w2t[(cob * 16 + col) * 72 + kb * 32 + quad * 8];
            gacc = __builtin_amdgcn_mfma_f32_16x16x32_bf16(a, bb, gacc, 0, 0, 0);
        }
        #pragma unroll
        for (int reg = 0; reg < 4; ++reg) {
            int pwr = quad * 4 + reg;
            int m = r * 32 + wb * 16 + pwr;
            g_o[((size_t)b * Mn + m) * 128 + cob * 16 + col] = gacc[reg];
        }
    }

    // ---- p from a4 pool ----
    if (tid < 16) {
        float s = 0.f;
        #pragma unroll 8
        for (int ic = 0; ic < 64; ++ic) {
            float pv = fmaxf(ph[tid * 68 + ic], ph[(16 + tid) * 68 + ic]) + b4[ic];
            s += w5[64 + ic] * pv;
        }
        p_o[(size_t)b * Mn + r * 32 + wb * 16 + tid] = s;
    }
}

// ---------------------------------------------------------------------------
// K3: rank-by-counting sort, parallel: 8 lanes per key, 32 keys per block.
// ---------------------------------------------------------------------------
__global__ __launch_bounds__(256) void k_rank(
    const float* __restrict__ p, float* __restrict__ ps, int* __restrict__ perm)
{
    const int seg = blockIdx.x;    // 0..31
    const int b   = blockIdx.y;
    const int tid = threadIdx.x;
    __shared__ float pls[1024];
    #pragma unroll
    for (int it = 0; it < 4; ++it) pls[tid + 256 * it] = p[b * 1024 + tid + 256 * it];
    __syncthreads();
    const int m = seg * 32 + (tid >> 3);
    const int sub = tid & 7;
    const float key = pls[m];
    int rank = 0;
    #pragma unroll 8
    for (int jj = 0; jj < 128; ++jj) {
        int j = sub + jj * 8;          // 8 distinct banks / broadcast across groups
        float v = pls[j];
        rank += (v < key || (v == key && j < m)) ? 1 : 0;
    }
    rank += __shfl_xor(rank, 1, 64);
    rank += __shfl_xor(rank, 2, 64);
    rank += __shfl_xor(rank, 4, 64);
    if (sub == 0) {
        ps[b * 1024 + rank]   = key;
        perm[b * 1024 + rank] = m;
    }
}

// ---------------------------------------------------------------------------
// K4: per 32-j segment chunk sums of g_sorted and p*g_sorted
// ---------------------------------------------------------------------------
__global__ __launch_bounds__(256) void k_scanA(
    const float* __restrict__ g, const float* __restrict__ ps, const int* __restrict__ perm,
    float* __restrict__ csa, float* __restrict__ csb)
{
    const int seg = blockIdx.x;
    const int b = blockIdx.y;
    const int tid = threadIdx.x;
    const int co = tid & 127, jh = tid >> 7;
    __shared__ float redA[2][128], redB[2][128];
    __shared__ float pl[32];
    __shared__ int   pml[32];
    if (tid < 32) { pl[tid] = ps[b * 1024 + seg * 32 + tid]; pml[tid] = perm[b * 1024 + seg * 32 + tid]; }
    __syncthreads();
    float sA = 0.f, sB = 0.f;
    for (int jj = jh * 16; jj < jh * 16 + 16; ++jj) {
        float gv = g[((size_t)b * Mn + pml[jj]) * 128 + co];
        sA += gv; sB += pl[jj] * gv;
    }
    redA[jh][co] = sA; redB[jh][co] = sB;
    __syncthreads();
    if (tid < 128) {
        csa[(b * 32 + seg) * 128 + tid] = redA[0][tid] + redA[1][tid];
        csb[(b * 32 + seg) * 128 + tid] = redB[0][tid] + redB[1][tid];
    }
}

// ---------------------------------------------------------------------------
// K5: suffix-sum walk -> SA[b][k][co], SB[b][k][co], k in [0,1024].
// ---------------------------------------------------------------------------
__global__ __launch_bounds__(256) void k_scanC(
    const float* __restrict__ g, const float* __restrict__ ps, const int* __restrict__ perm,
    const float* __restrict__ csa, const float* __restrict__ csb,
    float* __restrict__ SA, float* __restrict__ SB)
{
    const int seg = blockIdx.x;
    const int b = blockIdx.y;
    const int tid = threadIdx.x;
    __shared__ float gs[32 * 128];
    __shared__ float pl[32];
    __shared__ int   pml[32];
    if (tid < 32) { pl[tid] = ps[b * 1024 + seg * 32 + tid]; pml[tid] = perm[b * 1024 + seg * 32 + tid]; }
    __syncthreads();
    for (int it = 0; it < 16; ++it) {
        int f = tid + 256 * it;
        int jj = f >> 7, co = f & 127;
        gs[jj * 128 + co] = g[((size_t)b * Mn + pml[jj]) * 128 + co];
    }
    __syncthreads();

    const int co = tid & 127;
    if (tid < 128) {
        float rA = 0.f;
        for (int s = seg + 1; s < 32; ++s) rA += csa[(b * 32 + s) * 128 + co];
        if (seg == 31) SA[((size_t)b * 1025 + 1024) * 128 + co] = 0.f;
        for (int jj = 31; jj >= 0; --jj) {
            rA += gs[jj * 128 + co];
            SA[((size_t)b * 1025 + seg * 32 + jj) * 128 + co] = rA;
        }
    } else {
        float rB = 0.f;
        for (int s = seg + 1; s < 32; ++s) rB += csb[(b * 32 + s) * 128 + co];
        if (seg == 31) SB[((size_t)b * 1025 + 1024) * 128 + co] = 0.f;
        for (int jj = 31; jj >= 0; --jj) {
            rB += pl[jj] * gs[jj * 128 + co];
            SB[((size_t)b * 1025 + seg * 32 + jj) * 128 + co] = rB;
        }
    }
}

// ---------------------------------------------------------------------------
// K6: out[b][co][n] = ((t[n]*SA[k(n)][co] + SB[k(n)][co])/M)*sc[co] + bs[co] + x
// ---------------------------------------------------------------------------
__global__ __launch_bounds__(256) void k_final(
    const float* __restrict__ x, const float* __restrict__ t,
    const float* __restrict__ ps, const float* __restrict__ SA, const float* __restrict__ SB,
    const float* __restrict__ b2, const float* __restrict__ gamma, const float* __restrict__ beta,
    const float* __restrict__ mean, const float* __restrict__ var,
    float* __restrict__ out)
{
    const int nt = blockIdx.x;
    const int b = blockIdx.y;
    const int tid = threadIdx.x;
    const int n0 = nt * 128;
    __shared__ float psl[1024];
    __shared__ float tl[128];
    __shared__ int   kl[128];
    __shared__ float sc[128], bs[128];
    __shared__ float sa_s[32][129], sb_s[32][129];

    for (int it = 0; it < 4; ++it) psl[tid + 256 * it] = ps[b * 1024 + tid + 256 * it];
    __syncthreads();
    if (tid < 128) {
        float tv = t[(size_t)b * Nn + n0 + tid];
        tl[tid] = tv;
        float key = -tv;
        int lo = 0, hi = 1024;
        while (lo < hi) { int mid = (lo + hi) >> 1; if (psl[mid] > key) hi = mid; else lo = mid + 1; }
        kl[tid] = lo;
    } else {
        int co = tid - 128;
        float s = gamma[co] * rsqrtf(var[co] + 1e-5f);
        sc[co] = s;
        bs[co] = (b2[co] - mean[co]) * s + beta[co];
    }
    __syncthreads();

    const float invM = 1.0f / 1024.0f;
    for (int sub = 0; sub < 4; ++sub) {
        for (int it = 0; it < 16; ++it) {
            int f = tid + 256 * it;
            int rowl = f >> 7, co = f & 127;
            int k = kl[sub * 32 + rowl];
            sa_s[rowl][co] = SA[((size_t)b * 1025 + k) * 128 + co];
            sb_s[rowl][co] = SB[((size_t)b * 1025 + k) * 128 + co];
        }
        __syncthreads();
        for (int it = 0; it < 4; ++it) {
            int f = tid + 256 * it;
            int co = f >> 3, nn0 = (f & 7) * 4;
            size_t gidx = ((size_t)b * Cn + co) * Nn + n0 + sub * 32 + nn0;
            float4 xv = *(const float4*)&x[gidx];
            float scv = sc[co], bsv = bs[co];
            float4 o;
            float v0 = (tl[sub*32+nn0+0] * sa_s[nn0+0][co] + sb_s[nn0+0][co]) * invM;
            float v1 = (tl[sub*32+nn0+1] * sa_s[nn0+1][co] + sb_s[nn0+1][co]) * invM;
            float v2 = (tl[sub*32+nn0+2] * sa_s[nn0+2][co] + sb_s[nn0+2][co]) * invM;
            float v3 = (tl[sub*32+nn0+3] * sa_s[nn0+3][co] + sb_s[nn0+3][co]) * invM;
            o.x = v0 * scv + bsv + xv.x;
            o.y = v1 * scv + bsv + xv.y;
            o.z = v2 * scv + bsv + xv.z;
            o.w = v3 * scv + bsv + xv.w;
            *(float4*)&out[gidx] = o;
        }
        __syncthreads();
    }
}

// ---------------------------------------------------------------------------
extern "C" void kernel_launch(void* const* d_in, const int* in_sizes, int n_in,
                              void* d_out, int out_size, void* d_ws, size_t ws_size,
                              hipStream_t stream)
{
    const float* x  = (const float*)d_in[0];
    const float* w1 = (const float*)d_in[1];
    const float* b1 = (const float*)d_in[2];
    const float* w3 = (const float*)d_in[3];
    const float* b3 = (const float*)d_in[4];
    const float* w4 = (const float*)d_in[5];
    const float* b4 = (const float*)d_in[6];
    const float* w5 = (const float*)d_in[7];
    const float* w2 = (const float*)d_in[8];
    const float* b2 = (const float*)d_in[9];
    const float* gm = (const float*)d_in[10];
    const float* bt = (const float*)d_in[11];
    const float* mn = (const float*)d_in[12];
    const float* vr = (const float*)d_in[13];
    float* out = (float*)d_out;

    float* ws = (float*)d_ws;
    const size_t FTOT = 3823872;           // floats (~15.3 MB)
    if (ws_size < FTOT * sizeof(float)) return;

    float* t_w  = ws;                      // 32768
    float* p_w  = ws + 32768;              // 8192
    float* ps_w = ws + 40960;              // 8192
    int*   pm_w = (int*)(ws + 49152);      // 8192
    float* g_w  = ws + 581632;             // 1048576
    float* csa  = ws + 1630208;            // 32768
    float* csb  = ws + 1662976;            // 32768
    float* SAp  = ws + 1695744;            // 1049600
    float* SBp  = ws + 2745344;            // 1049600

    k_conv <<<dim3(64, 8), 256, 0, stream>>>(x, w1, b1, w3, b3, w4, b4, w5, w2,
                                             t_w, p_w, g_w);
    k_rank <<<dim3(32, 8), 256, 0, stream>>>(p_w, ps_w, pm_w);
    k_scanA<<<dim3(32, 8), 256, 0, stream>>>(g_w, ps_w, pm_w, csa, csb);
    k_scanC<<<dim3(32, 8), 256, 0, stream>>>(g_w, ps_w, pm_w, csa, csb, SAp, SBp);
    k_final<<<dim3(32, 8), 256, 0, stream>>>(x, t_w, ps_w, SAp, SBp, b2, gm, bt, mn, vr, out);
}

// Round 3
// 122.455 us; speedup vs baseline: 2.3473x; 1.0567x over previous
//
#include <hip/hip_runtime.h>

typedef unsigned int u32;
typedef unsigned short u16;

#define Cn 128
#define ICn 64
#define Nn 4096
#define Mn 1024

typedef __attribute__((ext_vector_type(8))) short s8v;   // 8 bf16 (4 VGPRs)
typedef __attribute__((ext_vector_type(4))) float f4v;   // 4 fp32 acc

__device__ __forceinline__ float bf2f(u16 u){ union{u32 i; float f;} v; v.i = ((u32)u) << 16; return v.f; }
__device__ __forceinline__ u16 f2bf(float f){ union{float f; u32 i;} v; v.f = f; u32 r = v.i + 0x7fffu + ((v.i >> 16) & 1u); return (u16)(r >> 16); }
__device__ __forceinline__ u32 pk2(float lo, float hi){ return (u32)f2bf(lo) | ((u32)f2bf(hi) << 16); }

// ---------------------------------------------------------------------------
// K1 (MFMA, weight-prep folded in): per (row-pair r, half-width wb, batch b).
// x^T staged as CHANNEL-PAIRS: each thread loads float4 from rows c,c+1 and
// writes 4x ds_write_b32 (2 bf16 each) -> halves LDS write instruction count.
// XOR swizzle col' = c ^ (((lp)>>2)&7)<<3 (pair-preserving: swz bit0 = 0).
// LDS u16 smem[32768] = 64 KB (layout unchanged from r2).
// ---------------------------------------------------------------------------
__global__ __launch_bounds__(256) void k_conv(
    const float* __restrict__ x,
    const float* __restrict__ w1, const float* __restrict__ b1,
    const float* __restrict__ w3, const float* __restrict__ b3,
    const float* __restrict__ w4, const float* __restrict__ b4,
    const float* __restrict__ w5, const float* __restrict__ w2,
    float* __restrict__ t_o, float* __restrict__ p_o, float* __restrict__ g_o)
{
    const int tile = blockIdx.x;   // 0..63
    const int r  = tile >> 1;      // row-pair 0..31
    const int wb = tile & 1;       // half-width 0..1
    const int b  = blockIdx.y;
    const int tid = threadIdx.x;

    __shared__ __align__(16) u16 smem[32768];
    u16* xsT = smem;               // [64][136]
    u16* w1t = smem + 8704;        // [64][136]
    u16* w4t = smem + 17408;       // [64][136]
    float* ph = (float*)&smem[26112]; // [32][68] f32
    u16* w2t = smem + 8704;        // phase B [128][72]
    u16* xgr = smem + 17920;       // phase B [16][72]
    float* u3s = (float*)&smem[30464]; // [129] f32

    // ---- stage x^T as bf16 channel-pairs, swizzled ----
    #pragma unroll
    for (int it = 0; it < 4; ++it) {
        int f = tid + 256 * it;        // 1024 tasks: cp = f>>4, rem = f&15
        int cp = f >> 4, rem = f & 15;
        int rl = rem >> 3, wq = rem & 7;
        const float* src = x + ((size_t)(b * Cn + 2 * cp)) * Nn + (2 * r + rl) * 64 + 32 * wb + 4 * wq;
        float4 v0 = *(const float4*)src;
        float4 v1 = *(const float4*)(src + Nn);
        int lp0 = rl * 32 + 4 * wq;
        int cS = (2 * cp) ^ (wq << 3); // ((lp0+k)>>2)&7 == wq for k=0..3
        *(u32*)&xsT[(lp0 + 0) * 136 + cS] = pk2(v0.x, v1.x);
        *(u32*)&xsT[(lp0 + 1) * 136 + cS] = pk2(v0.y, v1.y);
        *(u32*)&xsT[(lp0 + 2) * 136 + cS] = pk2(v0.z, v1.z);
        *(u32*)&xsT[(lp0 + 3) * 136 + cS] = pk2(v0.w, v1.w);
    }
    // ---- stage W1, W4: f32 load + convert + ds_write_b128 ----
    #pragma unroll
    for (int it = 0; it < 4; ++it) {
        int f = tid + 256 * it;        // 1024 groups of 8: ic = f>>4, cq = f&15
        int ic = f >> 4, cq = f & 15;
        const float4* s1 = (const float4*)&w1[f * 8];
        const float4* s4 = (const float4*)&w4[f * 8];
        float4 a0 = s1[0], a1v = s1[1];
        float4 d0 = s4[0], d1v = s4[1];
        uint4 A, D;
        A.x = pk2(a0.x, a0.y); A.y = pk2(a0.z, a0.w); A.z = pk2(a1v.x, a1v.y); A.w = pk2(a1v.z, a1v.w);
        D.x = pk2(d0.x, d0.y); D.y = pk2(d0.z, d0.w); D.z = pk2(d1v.x, d1v.y); D.w = pk2(d1v.z, d1v.w);
        *(uint4*)&w1t[ic * 136 + 8 * cq] = A;
        *(uint4*)&w4t[ic * 136 + 8 * cq] = D;
    }
    // ---- u3 = w5[:64].W3 (redundant, L2-resident), 2 accumulators ----
    if (tid < 128) {
        float s0 = 0.f, s1 = 0.f;
        #pragma unroll 8
        for (int ic = 0; ic < 64; ic += 2) {
            s0 += w5[ic]     * w3[ic * Cn + tid];
            s1 += w5[ic + 1] * w3[(ic + 1) * Cn + tid];
        }
        u3s[tid] = s0 + s1;
    } else if (tid == 128) {
        float s = 0.f;
        #pragma unroll 16
        for (int ic = 0; ic < 64; ++ic) s += w5[ic] * b3[ic];
        u3s[128] = s;
    }
    __syncthreads();

    const int lane = tid & 63;
    const int wv   = tid >> 6;         // wave 0..3 -> lp block [16wv,16wv+16)
    const int col  = lane & 15;
    const int quad = lane >> 4;

    // ---- dual conv MFMA: D[ic][lp] ----
    f4v acc1[4] = {}, acc4[4] = {};
    const u16* xrow = &xsT[(16 * wv + col) * 136];
    const int xsw = (((16 * wv + col) >> 2) & 7) << 3;
    #pragma unroll
    for (int kb = 0; kb < 4; ++kb) {
        s8v bx = *(const s8v*)&xrow[(kb * 32 + quad * 8) ^ xsw];
        #pragma unroll
        for (int icb = 0; icb < 4; ++icb) {
            s8v a1 = *(const s8v*)&w1t[(icb * 16 + col) * 136 + kb * 32 + quad * 8];
            s8v a4 = *(const s8v*)&w4t[(icb * 16 + col) * 136 + kb * 32 + quad * 8];
            acc1[icb] = __builtin_amdgcn_mfma_f32_16x16x32_bf16(a1, bx, acc1[icb], 0, 0, 0);
            acc4[icb] = __builtin_amdgcn_mfma_f32_16x16x32_bf16(a4, bx, acc4[icb], 0, 0, 0);
        }
    }
    __syncthreads();   // MFMA LDS reads done; w1t/w4t dead

    // ---- a1: horizontal pair max in-register, write half-pool to ph ----
    const int lp = 16 * wv + col;
    const int rl = lp >> 5, wl = lp & 31, pw = wl >> 1;
    const bool wr = (wl & 1) == 0;
    #pragma unroll
    for (int icb = 0; icb < 4; ++icb)
        #pragma unroll
        for (int reg = 0; reg < 4; ++reg) {
            float v = acc1[icb][reg];
            float vm = fmaxf(v, __shfl_xor(v, 1, 64));
            if (wr) ph[(rl * 16 + pw) * 68 + icb * 16 + quad * 4 + reg] = vm;
        }
    __syncthreads();

    // ---- xgr = vertical pool + bias (bf16) ----
    #pragma unroll
    for (int it = 0; it < 4; ++it) {
        int e = tid + 256 * it;        // 1024: pw = e>>6, ic = e&63
        int pwq = e >> 6, ic = e & 63;
        float v = fmaxf(ph[pwq * 68 + ic], ph[(16 + pwq) * 68 + ic]) + b1[ic];
        xgr[pwq * 72 + ic] = f2bf(v);
    }
    // ---- t = u3.x + c3, all 256 threads (4 lanes per pixel) ----
    {
        int px = tid >> 2, part = tid & 3;
        const int tsw = ((px >> 2) & 7) << 3;
        const u16* xr = &xsT[px * 136];
        float s = 0.f;
        #pragma unroll
        for (int cq = 0; cq < 4; ++cq) {
            int u = part * 32 + cq * 8;
            s8v xv = *(const s8v*)&xr[u ^ tsw];
            #pragma unroll
            for (int j = 0; j < 8; ++j) s += u3s[u + j] * bf2f((u16)xv[j]);
        }
        s += __shfl_xor(s, 1, 64);
        s += __shfl_xor(s, 2, 64);
        if (part == 0)
            t_o[(size_t)b * Nn + (2 * r + (px >> 5)) * 64 + 32 * wb + (px & 31)] = s + u3s[128];
    }
    __syncthreads();   // xgr ready; ph consumed

    // ---- stage W2 (f32->bf16) [co][72]; a4 half-pool -> ph ----
    #pragma unroll
    for (int it = 0; it < 4; ++it) {
        int f = tid + 256 * it;        // 1024 groups: co = f>>3, iq = f&7
        int co = f >> 3, iq = f & 7;
        const float4* s2 = (const float4*)&w2[f * 8];
        float4 a0 = s2[0], a1v = s2[1];
        uint4 V;
        V.x = pk2(a0.x, a0.y); V.y = pk2(a0.z, a0.w); V.z = pk2(a1v.x, a1v.y); V.w = pk2(a1v.z, a1v.w);
        *(uint4*)&w2t[co * 72 + 8 * iq] = V;
    }
    #pragma unroll
    for (int icb = 0; icb < 4; ++icb)
        #pragma unroll
        for (int reg = 0; reg < 4; ++reg) {
            float v = acc4[icb][reg];
            float vm = fmaxf(v, __shfl_xor(v, 1, 64));
            if (wr) ph[(rl * 16 + pw) * 68 + icb * 16 + quad * 4 + reg] = vm;
        }
    __syncthreads();

    // ---- g = xgr . W2^T via MFMA: wave wv -> co blocks {2wv, 2wv+1} ----
    #pragma unroll
    for (int cob2 = 0; cob2 < 2; ++cob2) {
        int cob = 2 * wv + cob2;
        f4v gacc = {};
        #pragma unroll
        for (int kb = 0; kb < 2; ++kb) {
            s8v a  = *(const s8v*)&xgr[col * 72 + kb * 32 + quad * 8];
            s8v bb = *(const s8v*)&w2t[(cob * 16 + col) * 72 + kb * 32 + quad * 8];
            gacc = __builtin_amdgcn_mfma_f32_16x16x32_bf16(a, bb, gacc, 0, 0, 0);
        }
        #pragma unroll
        for (int reg = 0; reg < 4; ++reg) {
            int pwr = quad * 4 + reg;
            int m = r * 32 + wb * 16 + pwr;
            g_o[((size_t)b * Mn + m) * 128 + cob * 16 + col] = gacc[reg];
        }
    }

    // ---- p from a4 pool ----
    if (tid < 16) {
        float s = 0.f;
        #pragma unroll 8
        for (int ic = 0; ic < 64; ++ic) {
            float pv = fmaxf(ph[tid * 68 + ic], ph[(16 + tid) * 68 + ic]) + b4[ic];
            s += w5[64 + ic] * pv;
        }
        p_o[(size_t)b * Mn + r * 32 + wb * 16 + tid] = s;
    }
}

// ---------------------------------------------------------------------------
// K3: rank-by-counting, 512 threads: 16 lanes per key, 32 keys per block.
// ---------------------------------------------------------------------------
__global__ __launch_bounds__(512) void k_rank(
    const float* __restrict__ p, float* __restrict__ ps, int* __restrict__ perm)
{
    const int seg = blockIdx.x;    // 0..31
    const int b   = blockIdx.y;
    const int tid = threadIdx.x;
    __shared__ float pls[1024];
    #pragma unroll
    for (int it = 0; it < 2; ++it) pls[tid + 512 * it] = p[b * 1024 + tid + 512 * it];
    __syncthreads();
    const int m = seg * 32 + (tid >> 4);
    const int sub = tid & 15;
    const float key = pls[m];
    int rank = 0;
    #pragma unroll 8
    for (int jj = 0; jj < 64; ++jj) {
        int j = sub + jj * 16;
        float v = pls[j];
        rank += (v < key || (v == key && j < m)) ? 1 : 0;
    }
    rank += __shfl_xor(rank, 1, 64);
    rank += __shfl_xor(rank, 2, 64);
    rank += __shfl_xor(rank, 4, 64);
    rank += __shfl_xor(rank, 8, 64);
    if (sub == 0) {
        ps[b * 1024 + rank]   = key;
        perm[b * 1024 + rank] = m;
    }
}

// ---------------------------------------------------------------------------
// K4: per 32-j segment chunk sums -> csab[seg][co] = {sum g, sum p*g} (float2)
// ---------------------------------------------------------------------------
__global__ __launch_bounds__(512) void k_scanA(
    const float* __restrict__ g, const float* __restrict__ ps, const int* __restrict__ perm,
    float2* __restrict__ csab)
{
    const int seg = blockIdx.x;
    const int b = blockIdx.y;
    const int tid = threadIdx.x;
    const int co = tid & 127, jh = tid >> 7;   // jh 0..3
    __shared__ float redA[4][128], redB[4][128];
    __shared__ float pl[32];
    __shared__ int   pml[32];
    if (tid < 32) { pl[tid] = ps[b * 1024 + seg * 32 + tid]; pml[tid] = perm[b * 1024 + seg * 32 + tid]; }
    __syncthreads();
    float sA = 0.f, sB = 0.f;
    #pragma unroll
    for (int jj = jh * 8; jj < jh * 8 + 8; ++jj) {
        float gv = g[((size_t)b * Mn + pml[jj]) * 128 + co];
        sA += gv; sB += pl[jj] * gv;
    }
    redA[jh][co] = sA; redB[jh][co] = sB;
    __syncthreads();
    if (tid < 128) {
        float2 v;
        v.x = (redA[0][tid] + redA[1][tid]) + (redA[2][tid] + redA[3][tid]);
        v.y = (redB[0][tid] + redB[1][tid]) + (redB[2][tid] + redB[3][tid]);
        csab[(b * 32 + seg) * 128 + tid] = v;
    }
}

// ---------------------------------------------------------------------------
// K5: suffix-sum walk -> SAB[b][k][co] = {SA, SB} (float2), k in [0,1024].
// 512 threads: all stage gs; threads 0..127 (=co) do both walks + float2 write.
// ---------------------------------------------------------------------------
__global__ __launch_bounds__(512) void k_scanC(
    const float* __restrict__ g, const float* __restrict__ ps, const int* __restrict__ perm,
    const float2* __restrict__ csab, float2* __restrict__ SAB)
{
    const int seg = blockIdx.x;
    const int b = blockIdx.y;
    const int tid = threadIdx.x;
    __shared__ float gs[32 * 128];
    __shared__ float pl[32];
    __shared__ int   pml[32];
    if (tid < 32) { pl[tid] = ps[b * 1024 + seg * 32 + tid]; pml[tid] = perm[b * 1024 + seg * 32 + tid]; }
    __syncthreads();
    #pragma unroll
    for (int it = 0; it < 8; ++it) {
        int f = tid + 512 * it;
        int jj = f >> 7, co = f & 127;
        gs[jj * 128 + co] = g[((size_t)b * Mn + pml[jj]) * 128 + co];
    }
    __syncthreads();

    if (tid < 128) {
        const int co = tid;
        float rA = 0.f, rB = 0.f;
        #pragma unroll 4
        for (int s2 = seg + 1; s2 < 32; ++s2) {
            float2 v = csab[(b * 32 + s2) * 128 + co];
            rA += v.x; rB += v.y;
        }
        if (seg == 31) SAB[((size_t)b * 1025 + 1024) * 128 + co] = make_float2(0.f, 0.f);
        #pragma unroll
        for (int jj = 31; jj >= 0; --jj) {
            float gv = gs[jj * 128 + co];
            rA += gv;
            rB += pl[jj] * gv;
            SAB[((size_t)b * 1025 + seg * 32 + jj) * 128 + co] = make_float2(rA, rB);
        }
    }
}

// ---------------------------------------------------------------------------
// K6: out = ((t[n]*SA[k(n)][co] + SB[k(n)][co])/M)*sc[co] + bs[co] + x
// 512 threads; SA/SB prefetched per-sub into registers (overlap with compute).
// ---------------------------------------------------------------------------
__global__ __launch_bounds__(512) void k_final(
    const float* __restrict__ x, const float* __restrict__ t,
    const float* __restrict__ ps, const float2* __restrict__ SAB,
    const float* __restrict__ b2, const float* __restrict__ gamma, const float* __restrict__ beta,
    const float* __restrict__ mean, const float* __restrict__ var,
    float* __restrict__ out)
{
    const int nt = blockIdx.x;
    const int b = blockIdx.y;
    const int tid = threadIdx.x;
    const int n0 = nt * 128;
    __shared__ float psl[1024];
    __shared__ float tl[128];
    __shared__ int   kl[128];
    __shared__ float sc[128], bs[128];
    __shared__ float sa_s[32][129], sb_s[32][129];

    #pragma unroll
    for (int it = 0; it < 2; ++it) psl[tid + 512 * it] = ps[b * 1024 + tid + 512 * it];
    __syncthreads();
    if (tid < 128) {
        float tv = t[(size_t)b * Nn + n0 + tid];
        tl[tid] = tv;
        float key = -tv;
        int lo = 0, hi = 1024;
        while (lo < hi) { int mid = (lo + hi) >> 1; if (psl[mid] > key) hi = mid; else lo = mid + 1; }
        kl[tid] = lo;
    } else if (tid < 256) {
        int co = tid - 128;
        float s = gamma[co] * rsqrtf(var[co] + 1e-5f);
        sc[co] = s * (1.0f / 1024.0f);             // fold 1/M into BN scale
        bs[co] = (b2[co] - mean[co]) * s + beta[co];
    }
    __syncthreads();

    // prefetch pipeline: 8 float2 rows per thread per sub
    float2 pf[8], pf2[8];
    {
        #pragma unroll
        for (int i2 = 0; i2 < 8; ++i2) {
            int f = tid + 512 * i2;
            int rowl = f >> 7, co = f & 127;
            pf[i2] = SAB[((size_t)b * 1025 + kl[rowl]) * 128 + co];
        }
    }
    for (int sub = 0; sub < 4; ++sub) {
        #pragma unroll
        for (int i2 = 0; i2 < 8; ++i2) {
            int f = tid + 512 * i2;
            int rowl = f >> 7, co = f & 127;
            sa_s[rowl][co] = pf[i2].x;
            sb_s[rowl][co] = pf[i2].y;
        }
        if (sub < 3) {
            #pragma unroll
            for (int i2 = 0; i2 < 8; ++i2) {
                int f = tid + 512 * i2;
                int rowl = f >> 7, co = f & 127;
                pf2[i2] = SAB[((size_t)b * 1025 + kl[(sub + 1) * 32 + rowl]) * 128 + co];
            }
        }
        __syncthreads();
        #pragma unroll
        for (int it = 0; it < 2; ++it) {
            int f = tid + 512 * it;
            int co = f >> 3, nn0 = (f & 7) * 4;
            size_t gidx = ((size_t)b * Cn + co) * Nn + n0 + sub * 32 + nn0;
            float4 xv = *(const float4*)&x[gidx];
            float scv = sc[co], bsv = bs[co];
            float4 o;
            float v0 = tl[sub*32+nn0+0] * sa_s[nn0+0][co] + sb_s[nn0+0][co];
            float v1 = tl[sub*32+nn0+1] * sa_s[nn0+1][co] + sb_s[nn0+1][co];
            float v2 = tl[sub*32+nn0+2] * sa_s[nn0+2][co] + sb_s[nn0+2][co];
            float v3 = tl[sub*32+nn0+3] * sa_s[nn0+3][co] + sb_s[nn0+3][co];
            o.x = v0 * scv + bsv + xv.x;
            o.y = v1 * scv + bsv + xv.y;
            o.z = v2 * scv + bsv + xv.z;
            o.w = v3 * scv + bsv + xv.w;
            *(float4*)&out[gidx] = o;
        }
        __syncthreads();
        #pragma unroll
        for (int i2 = 0; i2 < 8; ++i2) pf[i2] = pf2[i2];
    }
}

// ---------------------------------------------------------------------------
extern "C" void kernel_launch(void* const* d_in, const int* in_sizes, int n_in,
                              void* d_out, int out_size, void* d_ws, size_t ws_size,
                              hipStream_t stream)
{
    const float* x  = (const float*)d_in[0];
    const float* w1 = (const float*)d_in[1];
    const float* b1 = (const float*)d_in[2];
    const float* w3 = (const float*)d_in[3];
    const float* b3 = (const float*)d_in[4];
    const float* w4 = (const float*)d_in[5];
    const float* b4 = (const float*)d_in[6];
    const float* w5 = (const float*)d_in[7];
    const float* w2 = (const float*)d_in[8];
    const float* b2 = (const float*)d_in[9];
    const float* gm = (const float*)d_in[10];
    const float* bt = (const float*)d_in[11];
    const float* mn = (const float*)d_in[12];
    const float* vr = (const float*)d_in[13];
    float* out = (float*)d_out;

    float* ws = (float*)d_ws;
    const size_t FTOT = 3823872;           // floats (~15.3 MB)
    if (ws_size < FTOT * sizeof(float)) return;

    float*  t_w  = ws;                      // 32768
    float*  p_w  = ws + 32768;              // 8192
    float*  ps_w = ws + 40960;              // 8192
    int*    pm_w = (int*)(ws + 49152);      // 8192
    float*  g_w  = ws + 581632;             // 1048576
    float2* csab = (float2*)(ws + 1630208); // 8192 float2 = 65536 fl
    float2* SAB  = (float2*)(ws + 1695744); // 1025*128*8 fl2 = 2099200 fl

    k_conv <<<dim3(64, 8), 256, 0, stream>>>(x, w1, b1, w3, b3, w4, b4, w5, w2,
                                             t_w, p_w, g_w);
    k_rank <<<dim3(32, 8), 512, 0, stream>>>(p_w, ps_w, pm_w);
    k_scanA<<<dim3(32, 8), 512, 0, stream>>>(g_w, ps_w, pm_w, csab);
    k_scanC<<<dim3(32, 8), 512, 0, stream>>>(g_w, ps_w, pm_w, csab, SAB);
    k_final<<<dim3(32, 8), 512, 0, stream>>>(x, t_w, ps_w, SAB, b2, gm, bt, mn, vr, out);
}